// Round 1
// baseline (232.695 us; speedup 1.0000x reference)
//
#include <hip/hip_runtime.h>

#define T_TOK 2048
#define DM    512
#define DFF   512
#define NE    16
#define LDK   72   // padded LDS row stride (ushorts): 144 B rotates banks by 4/row

typedef __attribute__((ext_vector_type(8))) short bf16x8;
typedef __attribute__((ext_vector_type(4))) float f32x4;
typedef __attribute__((ext_vector_type(8))) unsigned short us8;

__device__ __forceinline__ unsigned short f2bf(float f) {
  unsigned int u = __float_as_uint(f);
  u += 0x7fffu + ((u >> 16) & 1u);   // round-to-nearest-even
  return (unsigned short)(u >> 16);
}

// load 16 consecutive floats at p, convert to bf16, return as two us8
__device__ __forceinline__ void cvt16(const float* __restrict__ p, us8* o) {
  float4 v0 = *(const float4*)(p);
  float4 v1 = *(const float4*)(p + 4);
  float4 v2 = *(const float4*)(p + 8);
  float4 v3 = *(const float4*)(p + 12);
  us8 a, b;
  a[0]=f2bf(v0.x); a[1]=f2bf(v0.y); a[2]=f2bf(v0.z); a[3]=f2bf(v0.w);
  a[4]=f2bf(v1.x); a[5]=f2bf(v1.y); a[6]=f2bf(v1.z); a[7]=f2bf(v1.w);
  b[0]=f2bf(v2.x); b[1]=f2bf(v2.y); b[2]=f2bf(v2.z); b[3]=f2bf(v2.w);
  b[4]=f2bf(v3.x); b[5]=f2bf(v3.y); b[6]=f2bf(v3.z); b[7]=f2bf(v3.w);
  o[0]=a; o[1]=b;
}

#define MFMA(a,b,c) __builtin_amdgcn_mfma_f32_16x16x32_bf16((a),(b),(c),0,0,0)

// ---------------- router: logits -> sigmoid -> top3 -> per-expert lists ----
__global__ __launch_bounds__(256) void router_kernel(
    const float* __restrict__ x, const float* __restrict__ gw,
    const float* __restrict__ bias, int* __restrict__ counts,
    int* __restrict__ list, float* __restrict__ wgt)
{
  __shared__ float logits[32][NE];
  __shared__ int bcnt[NE], bbase[NE];
  __shared__ int   ee[32*3];
  __shared__ int   pp[32*3];
  __shared__ float gg[32*3];

  const int tid = threadIdx.x, lane = tid & 63, w = tid >> 6;
  if (tid < NE) bcnt[tid] = 0;
  const int e = lane & 15, part = lane >> 4;
  const int tok0 = blockIdx.x * 32;

  for (int tt = 0; tt < 8; ++tt) {
    const int tl = w * 8 + tt;
    const float* xr = x + (size_t)(tok0 + tl) * DM + part * 128;
    const float* wr = gw + (size_t)e * DM + part * 128;
    float acc = 0.f;
    #pragma unroll 8
    for (int i = 0; i < 128; i += 4) {
      float4 xv = *(const float4*)(xr + i);
      float4 wv = *(const float4*)(wr + i);
      acc += xv.x*wv.x + xv.y*wv.y + xv.z*wv.z + xv.w*wv.w;
    }
    acc += __shfl_xor(acc, 16);
    acc += __shfl_xor(acc, 32);
    if (part == 0) logits[tl][e] = acc;
  }
  __syncthreads();

  if (tid < 32) {
    float aff[NE], sc[NE];
    #pragma unroll
    for (int i = 0; i < NE; ++i) {
      float l = logits[tid][i];
      aff[i] = 1.f / (1.f + __expf(-l));
      sc[i]  = aff[i] + bias[i];
    }
    int sel[3]; float sa[3]; float sum = 0.f;
    #pragma unroll
    for (int k = 0; k < 3; ++k) {
      float best = -1e30f; int bi = 0;
      for (int i = 0; i < NE; ++i) {
        bool used = false;
        for (int j = 0; j < k; ++j) used |= (sel[j] == i);
        if (!used && sc[i] > best) { best = sc[i]; bi = i; }
      }
      sel[k] = bi; sa[k] = aff[bi]; sum += aff[bi];
    }
    float inv = 1.f / (sum + 1e-9f);
    #pragma unroll
    for (int k = 0; k < 3; ++k) {
      int p = atomicAdd(&bcnt[sel[k]], 1);
      ee[tid*3+k] = sel[k]; pp[tid*3+k] = p; gg[tid*3+k] = sa[k] * inv;
    }
  }
  __syncthreads();
  if (tid < NE) bbase[tid] = atomicAdd(&counts[tid], bcnt[tid]);
  __syncthreads();
  if (tid < 32) {
    #pragma unroll
    for (int k = 0; k < 3; ++k) {
      int e2 = ee[tid*3+k];
      int pos = bbase[e2] + pp[tid*3+k];
      list[e2*T_TOK + pos] = tok0 + tid;
      wgt [e2*T_TOK + pos] = gg[tid*3+k];
    }
  }
}

__global__ void prefix_kernel(const int* __restrict__ counts, int* __restrict__ Hbase) {
  if (threadIdx.x == 0) {
    int s = 0;
    for (int i = 0; i < NE; ++i) { Hbase[i] = s; s += counts[i]; }
  }
}

// ---------------- GEMM1: x @ Wgu^T, fused silu(gate)*up -> H (bf16) --------
template<bool ROUTED>
__global__ __launch_bounds__(256) void gemm1_kernel(
    const float* __restrict__ x, const float* __restrict__ Wall,
    unsigned short* __restrict__ H,
    const int* __restrict__ counts, const int* __restrict__ Hbase,
    const int* __restrict__ list)
{
  __shared__ unsigned short As[64][LDK];
  __shared__ unsigned short Bg[64][LDK];
  __shared__ unsigned short Bu[64][LDK];

  const int n0 = blockIdx.x * 64;
  const int mt = blockIdx.y;
  const int e  = blockIdx.z;

  int cnt, hb;
  const float* W;
  if (ROUTED) {
    cnt = counts[e];
    if (mt * 64 >= cnt) return;
    hb = Hbase[e];
    W = Wall + (size_t)e * (2 * DFF * DM);
  } else { cnt = T_TOK; hb = 0; W = Wall; }

  const int tid = threadIdx.x;
  const int sr = tid >> 2;          // staging row 0..63
  const int sc = (tid & 3) * 16;    // staging col base

  const int entry = mt * 64 + sr;
  const bool avalid = entry < cnt;
  const float* arow = x;
  if (avalid) {
    int tok = ROUTED ? list[e * T_TOK + entry] : entry;
    arow = x + (size_t)tok * DM;
  }
  const float* grow = W + (size_t)(n0 + sr) * DM;
  const float* urow = W + (size_t)(DFF + n0 + sr) * DM;

  const int lane = tid & 63;
  const int wm = ((tid >> 6) & 1) * 32;
  const int wn = ((tid >> 7) & 1) * 32;
  const int lr = lane & 15;
  const int qd = lane >> 4;

  const f32x4 z4 = {0.f, 0.f, 0.f, 0.f};
  f32x4 accg[2][2], accu[2][2];
  #pragma unroll
  for (int i = 0; i < 2; ++i)
    #pragma unroll
    for (int j = 0; j < 2; ++j) { accg[i][j] = z4; accu[i][j] = z4; }

  for (int k0 = 0; k0 < DM; k0 += 64) {
    us8 av[2] = {{0,0,0,0,0,0,0,0},{0,0,0,0,0,0,0,0}};
    us8 gv[2], uv[2];
    if (avalid) cvt16(arow + k0 + sc, av);
    cvt16(grow + k0 + sc, gv);
    cvt16(urow + k0 + sc, uv);
    __syncthreads();
    *(us8*)&As[sr][sc] = av[0]; *(us8*)&As[sr][sc+8] = av[1];
    *(us8*)&Bg[sr][sc] = gv[0]; *(us8*)&Bg[sr][sc+8] = gv[1];
    *(us8*)&Bu[sr][sc] = uv[0]; *(us8*)&Bu[sr][sc+8] = uv[1];
    __syncthreads();
    #pragma unroll
    for (int ks = 0; ks < 2; ++ks) {
      const int kk = ks * 32 + qd * 8;
      bf16x8 a0 = *(const bf16x8*)&As[wm      + lr][kk];
      bf16x8 a1 = *(const bf16x8*)&As[wm + 16 + lr][kk];
      bf16x8 g0 = *(const bf16x8*)&Bg[wn      + lr][kk];
      bf16x8 g1 = *(const bf16x8*)&Bg[wn + 16 + lr][kk];
      bf16x8 u0 = *(const bf16x8*)&Bu[wn      + lr][kk];
      bf16x8 u1 = *(const bf16x8*)&Bu[wn + 16 + lr][kk];
      accg[0][0] = MFMA(a0, g0, accg[0][0]);
      accg[0][1] = MFMA(a0, g1, accg[0][1]);
      accg[1][0] = MFMA(a1, g0, accg[1][0]);
      accg[1][1] = MFMA(a1, g1, accg[1][1]);
      accu[0][0] = MFMA(a0, u0, accu[0][0]);
      accu[0][1] = MFMA(a0, u1, accu[0][1]);
      accu[1][0] = MFMA(a1, u0, accu[1][0]);
      accu[1][1] = MFMA(a1, u1, accu[1][1]);
    }
  }

  #pragma unroll
  for (int sm = 0; sm < 2; ++sm)
    #pragma unroll
    for (int sn = 0; sn < 2; ++sn) {
      const int col = n0 + wn + sn * 16 + lr;
      #pragma unroll
      for (int r = 0; r < 4; ++r) {
        const int ent = mt * 64 + wm + sm * 16 + qd * 4 + r;
        if (ent < cnt) {
          float g = accg[sm][sn][r];
          float u = accu[sm][sn][r];
          float h = (g / (1.f + __expf(-g))) * u;   // silu(g)*u
          H[(size_t)(hb + ent) * DFF + col] = f2bf(h);
        }
      }
    }
}

// ---------------- GEMM2: H @ Wd^T -> out (shared: store; routed: atomicAdd)-
template<bool ROUTED>
__global__ __launch_bounds__(256) void gemm2_kernel(
    const unsigned short* __restrict__ H, const float* __restrict__ Wall,
    float* __restrict__ out,
    const int* __restrict__ counts, const int* __restrict__ Hbase,
    const int* __restrict__ list, const float* __restrict__ wgt)
{
  __shared__ unsigned short Ah[64][LDK];
  __shared__ unsigned short Bd[64][LDK];

  const int n0 = blockIdx.x * 64;
  const int mt = blockIdx.y;
  const int e  = blockIdx.z;

  int cnt, hb;
  const float* W;
  if (ROUTED) {
    cnt = counts[e];
    if (mt * 64 >= cnt) return;
    hb = Hbase[e];
    W = Wall + (size_t)e * (DM * DFF);
  } else { cnt = T_TOK; hb = 0; W = Wall; }

  const int tid = threadIdx.x;
  const int sr = tid >> 2;
  const int sc = (tid & 3) * 16;
  const int entry = mt * 64 + sr;
  const bool avalid = entry < cnt;
  const unsigned short* arow = H;
  if (avalid) arow = H + (size_t)(hb + entry) * DFF;
  const float* drow = W + (size_t)(n0 + sr) * DFF;

  const int lane = tid & 63;
  const int wm = ((tid >> 6) & 1) * 32;
  const int wn = ((tid >> 7) & 1) * 32;
  const int lr = lane & 15;
  const int qd = lane >> 4;

  const f32x4 z4 = {0.f, 0.f, 0.f, 0.f};
  f32x4 acc[2][2];
  #pragma unroll
  for (int i = 0; i < 2; ++i)
    #pragma unroll
    for (int j = 0; j < 2; ++j) acc[i][j] = z4;

  for (int k0 = 0; k0 < DFF; k0 += 64) {
    us8 av0 = {0,0,0,0,0,0,0,0}, av1 = {0,0,0,0,0,0,0,0};
    if (avalid) {
      av0 = *(const us8*)(arow + k0 + sc);
      av1 = *(const us8*)(arow + k0 + sc + 8);
    }
    us8 dv[2];
    cvt16(drow + k0 + sc, dv);
    __syncthreads();
    *(us8*)&Ah[sr][sc] = av0;  *(us8*)&Ah[sr][sc+8] = av1;
    *(us8*)&Bd[sr][sc] = dv[0]; *(us8*)&Bd[sr][sc+8] = dv[1];
    __syncthreads();
    #pragma unroll
    for (int ks = 0; ks < 2; ++ks) {
      const int kk = ks * 32 + qd * 8;
      bf16x8 a0 = *(const bf16x8*)&Ah[wm      + lr][kk];
      bf16x8 a1 = *(const bf16x8*)&Ah[wm + 16 + lr][kk];
      bf16x8 b0 = *(const bf16x8*)&Bd[wn      + lr][kk];
      bf16x8 b1 = *(const bf16x8*)&Bd[wn + 16 + lr][kk];
      acc[0][0] = MFMA(a0, b0, acc[0][0]);
      acc[0][1] = MFMA(a0, b1, acc[0][1]);
      acc[1][0] = MFMA(a1, b0, acc[1][0]);
      acc[1][1] = MFMA(a1, b1, acc[1][1]);
    }
  }

  #pragma unroll
  for (int sm = 0; sm < 2; ++sm)
    #pragma unroll
    for (int sn = 0; sn < 2; ++sn) {
      const int col = n0 + wn + sn * 16 + lr;
      #pragma unroll
      for (int r = 0; r < 4; ++r) {
        const int ent = mt * 64 + wm + sm * 16 + qd * 4 + r;
        if (ent < cnt) {
          float v = acc[sm][sn][r];
          if (ROUTED) {
            int   tok = list[e * T_TOK + ent];
            float g   = wgt [e * T_TOK + ent];
            atomicAdd(out + (size_t)tok * DM + col, g * v);
          } else {
            out[(size_t)ent * DM + col] = v;
          }
        }
      }
    }
}

// ---------------------------------------------------------------------------
extern "C" void kernel_launch(void* const* d_in, const int* in_sizes, int n_in,
                              void* d_out, int out_size, void* d_ws, size_t ws_size,
                              hipStream_t stream) {
  const float* x    = (const float*)d_in[0];
  const float* gw   = (const float*)d_in[1];
  const float* bias = (const float*)d_in[2];
  const float* sgu  = (const float*)d_in[3];
  const float* sdn  = (const float*)d_in[4];
  const float* egu  = (const float*)d_in[5];
  const float* edn  = (const float*)d_in[6];
  float* out = (float*)d_out;

  // workspace layout (bytes)
  char* ws = (char*)d_ws;
  int*            counts = (int*)(ws + 0);          // 16 ints
  int*            Hbase  = (int*)(ws + 64);         // 16 ints
  int*            list   = (int*)(ws + 128);        // 16*2048 ints
  float*          wgt    = (float*)(ws + 131200);   // 16*2048 floats
  unsigned short* Hs     = (unsigned short*)(ws + 262400);   // 2048*512 bf16
  unsigned short* Hr     = (unsigned short*)(ws + 2359552);  // 6144*512 bf16
  if (ws_size < 8651008) return;

  hipMemsetAsync(counts, 0, 64, stream);
  router_kernel<<<64, 256, 0, stream>>>(x, gw, bias, counts, list, wgt);
  prefix_kernel<<<1, 64, 0, stream>>>(counts, Hbase);

  // shared expert
  gemm1_kernel<false><<<dim3(8, 32, 1), 256, 0, stream>>>(x, sgu, Hs, counts, Hbase, list);
  // routed experts
  gemm1_kernel<true ><<<dim3(8, 32, NE), 256, 0, stream>>>(x, egu, Hr, counts, Hbase, list);
  // shared down-proj writes out (every element exactly once)
  gemm2_kernel<false><<<dim3(8, 32, 1), 256, 0, stream>>>(Hs, sdn, out, counts, Hbase, list, wgt);
  // routed down-proj accumulates gated contributions
  gemm2_kernel<true ><<<dim3(8, 32, NE), 256, 0, stream>>>(Hr, edn, out, counts, Hbase, list, wgt);
}

// Round 2
// 184.099 us; speedup vs baseline: 1.2640x; 1.2640x over previous
//
#include <hip/hip_runtime.h>

#define T_TOK 2048
#define DM    512
#define DFF   512
#define NE    16
#define LDK   72   // padded LDS row stride (ushorts): 144 B rotates banks by 4/row

typedef __attribute__((ext_vector_type(8))) short bf16x8;
typedef __attribute__((ext_vector_type(4))) float f32x4;
typedef __attribute__((ext_vector_type(8))) unsigned short us8;

__device__ __forceinline__ unsigned short f2bf(float f) {
  unsigned int u = __float_as_uint(f);
  u += 0x7fffu + ((u >> 16) & 1u);   // round-to-nearest-even
  return (unsigned short)(u >> 16);
}

// load 16 consecutive floats at p, convert to bf16
__device__ __forceinline__ void cvt16(const float* __restrict__ p, us8* o) {
  float4 v0 = *(const float4*)(p);
  float4 v1 = *(const float4*)(p + 4);
  float4 v2 = *(const float4*)(p + 8);
  float4 v3 = *(const float4*)(p + 12);
  us8 a, b;
  a[0]=f2bf(v0.x); a[1]=f2bf(v0.y); a[2]=f2bf(v0.z); a[3]=f2bf(v0.w);
  a[4]=f2bf(v1.x); a[5]=f2bf(v1.y); a[6]=f2bf(v1.z); a[7]=f2bf(v1.w);
  b[0]=f2bf(v2.x); b[1]=f2bf(v2.y); b[2]=f2bf(v2.z); b[3]=f2bf(v2.w);
  b[4]=f2bf(v3.x); b[5]=f2bf(v3.y); b[6]=f2bf(v3.z); b[7]=f2bf(v3.w);
  o[0]=a; o[1]=b;
}

// stage 16 elements: PRE = already-bf16 source (2 us8 loads), else fp32+convert
template<bool PRE>
__device__ __forceinline__ void stage16(const void* __restrict__ base, size_t off, us8* o) {
  if constexpr (PRE) {
    const unsigned short* p = (const unsigned short*)base + off;
    o[0] = *(const us8*)p;
    o[1] = *(const us8*)(p + 8);
  } else {
    cvt16((const float*)base + off, o);
  }
}

#define MFMA(a,b,c) __builtin_amdgcn_mfma_f32_16x16x32_bf16((a),(b),(c),0,0,0)

// ---------------- router: one token per wave, 512 blocks -------------------
__global__ __launch_bounds__(256) void router_kernel(
    const float* __restrict__ x, const float* __restrict__ gw,
    const float* __restrict__ bias, int* __restrict__ counts,
    int* __restrict__ list, float* __restrict__ wgt)
{
  __shared__ float lg[4][16];
  __shared__ int bcnt[16], bbase[16];
  __shared__ int sel_s[4][3], pos_s[4][3];
  __shared__ float g_s[4][3];

  const int tid = threadIdx.x, w = tid >> 6, lane = tid & 63;
  if (tid < 16) bcnt[tid] = 0;
  const int tok = blockIdx.x * 4 + w;
  const int e = lane & 15, part = lane >> 4;

  const float* xr = x + (size_t)tok * DM + part * 128;  // broadcast across 16 e-lanes
  const float* wr = gw + (size_t)e * DM + part * 128;
  float acc = 0.f;
  #pragma unroll 8
  for (int i = 0; i < 128; i += 4) {
    float4 xv = *(const float4*)(xr + i);
    float4 wv = *(const float4*)(wr + i);
    acc += xv.x*wv.x + xv.y*wv.y + xv.z*wv.z + xv.w*wv.w;
  }
  acc += __shfl_xor(acc, 16);
  acc += __shfl_xor(acc, 32);
  if (lane < 16) lg[w][lane] = 1.f / (1.f + __expf(-acc));  // affinity
  __syncthreads();

  if (tid < 4) {
    float aff[16], sc[16];
    #pragma unroll
    for (int i = 0; i < 16; ++i) { aff[i] = lg[tid][i]; sc[i] = aff[i] + bias[i]; }
    int sel[3]; float sa[3]; float sum = 0.f;
    #pragma unroll
    for (int k = 0; k < 3; ++k) {
      float best = -1e30f; int bi = 0;
      for (int i = 0; i < 16; ++i) {
        bool used = false;
        for (int j = 0; j < k; ++j) used |= (sel[j] == i);
        if (!used && sc[i] > best) { best = sc[i]; bi = i; }
      }
      sel[k] = bi; sa[k] = aff[bi]; sum += aff[bi];
    }
    float inv = 1.f / (sum + 1e-9f);
    #pragma unroll
    for (int k = 0; k < 3; ++k) {
      int p = atomicAdd(&bcnt[sel[k]], 1);
      sel_s[tid][k] = sel[k]; pos_s[tid][k] = p; g_s[tid][k] = sa[k] * inv;
    }
  }
  __syncthreads();
  if (tid < 16) bbase[tid] = atomicAdd(&counts[tid], bcnt[tid]);
  __syncthreads();
  if (tid < 4) {
    #pragma unroll
    for (int k = 0; k < 3; ++k) {
      int E = sel_s[tid][k];
      int p = bbase[E] + pos_s[tid][k];
      list[E * T_TOK + p] = blockIdx.x * 4 + tid;
      wgt [E * T_TOK + p] = g_s[tid][k];
    }
  }
}

// ---------------- fp32 -> bf16 pre-convert (x + all 4 weight tensors) ------
// group = 8 elements; boundaries in groups:
//   x 131072 | sgu 65536 | sdn 32768 | egu 1048576 | edn 524288  (cum 1802240)
__global__ __launch_bounds__(256) void conv_kernel(
    const float* __restrict__ x,   const float* __restrict__ sgu,
    const float* __restrict__ sdn, const float* __restrict__ egu,
    const float* __restrict__ edn,
    unsigned short* __restrict__ xb,   unsigned short* __restrict__ sgub,
    unsigned short* __restrict__ sdnb, unsigned short* __restrict__ egub,
    unsigned short* __restrict__ ednb)
{
  int g = blockIdx.x * 256 + threadIdx.x;
  const float* s; unsigned short* d; int l;
  if      (g <  131072) { s = x;   d = xb;   l = g;           }
  else if (g <  196608) { s = sgu; d = sgub; l = g -  131072; }
  else if (g <  229376) { s = sdn; d = sdnb; l = g -  196608; }
  else if (g < 1277952) { s = egu; d = egub; l = g -  229376; }
  else                  { s = edn; d = ednb; l = g - 1277952; }
  const float* p = s + (size_t)l * 8;
  float4 v0 = *(const float4*)p;
  float4 v1 = *(const float4*)(p + 4);
  us8 o;
  o[0]=f2bf(v0.x); o[1]=f2bf(v0.y); o[2]=f2bf(v0.z); o[3]=f2bf(v0.w);
  o[4]=f2bf(v1.x); o[5]=f2bf(v1.y); o[6]=f2bf(v1.z); o[7]=f2bf(v1.w);
  *(us8*)(d + (size_t)l * 8) = o;
}

// ---------------- GEMM1 fused: z=0 shared, z>=1 expert z-1 -----------------
template<bool PRE>
__global__ __launch_bounds__(256) void gemm1_fused(
    const void* __restrict__ X, const void* __restrict__ Wsh,
    const void* __restrict__ Wex, unsigned short* __restrict__ Hall,
    const int* __restrict__ counts, const int* __restrict__ list)
{
  __shared__ unsigned short As[64][LDK];
  __shared__ unsigned short Bg[64][LDK];
  __shared__ unsigned short Bu[64][LDK];

  const int n0 = blockIdx.x * 64, mt = blockIdx.y, z = blockIdx.z;
  int cnt, hb; const void* W; size_t woff = 0;
  if (z == 0) { cnt = T_TOK; hb = 0; W = Wsh; }
  else {
    const int e = z - 1;
    cnt = counts[e];
    if (mt * 64 >= cnt) return;
    hb = T_TOK;
    for (int i = 0; i < e; ++i) hb += counts[i];
    W = Wex; woff = (size_t)e * (2 * DFF * DM);
  }

  const int tid = threadIdx.x;
  const int sr = tid >> 2;          // staging row 0..63
  const int sc = (tid & 3) * 16;    // staging col base
  const int entry = mt * 64 + sr;
  const bool avalid = entry < cnt;
  size_t aoff = 0;
  if (avalid) {
    int tok = (z == 0) ? entry : list[(z - 1) * T_TOK + entry];
    aoff = (size_t)tok * DM;
  }
  const size_t goff = woff + (size_t)(n0 + sr) * DM;
  const size_t uoff = woff + (size_t)(DFF + n0 + sr) * DM;

  const int lane = tid & 63;
  const int wm = ((tid >> 6) & 1) * 32;
  const int wn = ((tid >> 7) & 1) * 32;
  const int lr = lane & 15;
  const int qd = lane >> 4;

  const f32x4 z4 = {0.f, 0.f, 0.f, 0.f};
  f32x4 accg[2][2], accu[2][2];
  #pragma unroll
  for (int i = 0; i < 2; ++i)
    #pragma unroll
    for (int j = 0; j < 2; ++j) { accg[i][j] = z4; accu[i][j] = z4; }

  for (int k0 = 0; k0 < DM; k0 += 64) {
    us8 av[2] = {{0,0,0,0,0,0,0,0},{0,0,0,0,0,0,0,0}};
    us8 gv[2], uv[2];
    if (avalid) stage16<PRE>(X, aoff + k0 + sc, av);
    stage16<PRE>(W, goff + k0 + sc, gv);
    stage16<PRE>(W, uoff + k0 + sc, uv);
    __syncthreads();
    *(us8*)&As[sr][sc] = av[0]; *(us8*)&As[sr][sc+8] = av[1];
    *(us8*)&Bg[sr][sc] = gv[0]; *(us8*)&Bg[sr][sc+8] = gv[1];
    *(us8*)&Bu[sr][sc] = uv[0]; *(us8*)&Bu[sr][sc+8] = uv[1];
    __syncthreads();
    #pragma unroll
    for (int ks = 0; ks < 2; ++ks) {
      const int kk = ks * 32 + qd * 8;
      bf16x8 a0 = *(const bf16x8*)&As[wm      + lr][kk];
      bf16x8 a1 = *(const bf16x8*)&As[wm + 16 + lr][kk];
      bf16x8 g0 = *(const bf16x8*)&Bg[wn      + lr][kk];
      bf16x8 g1 = *(const bf16x8*)&Bg[wn + 16 + lr][kk];
      bf16x8 u0 = *(const bf16x8*)&Bu[wn      + lr][kk];
      bf16x8 u1 = *(const bf16x8*)&Bu[wn + 16 + lr][kk];
      accg[0][0] = MFMA(a0, g0, accg[0][0]);
      accg[0][1] = MFMA(a0, g1, accg[0][1]);
      accg[1][0] = MFMA(a1, g0, accg[1][0]);
      accg[1][1] = MFMA(a1, g1, accg[1][1]);
      accu[0][0] = MFMA(a0, u0, accu[0][0]);
      accu[0][1] = MFMA(a0, u1, accu[0][1]);
      accu[1][0] = MFMA(a1, u0, accu[1][0]);
      accu[1][1] = MFMA(a1, u1, accu[1][1]);
    }
  }

  #pragma unroll
  for (int sm = 0; sm < 2; ++sm)
    #pragma unroll
    for (int sn = 0; sn < 2; ++sn) {
      const int col = n0 + wn + sn * 16 + lr;
      #pragma unroll
      for (int r = 0; r < 4; ++r) {
        const int ent = mt * 64 + wm + sm * 16 + qd * 4 + r;
        if (ent < cnt) {
          float g = accg[sm][sn][r];
          float u = accu[sm][sn][r];
          float h = (g / (1.f + __expf(-g))) * u;   // silu(g)*u
          Hall[(size_t)(hb + ent) * DFF + col] = f2bf(h);
        }
      }
    }
}

// ---------------- GEMM2 fused: all-atomic epilogue into pre-zeroed out -----
template<bool PRE>
__global__ __launch_bounds__(256) void gemm2_fused(
    const unsigned short* __restrict__ Hall, const void* __restrict__ Wsh,
    const void* __restrict__ Wex, float* __restrict__ out,
    const int* __restrict__ counts, const int* __restrict__ list,
    const float* __restrict__ wgt)
{
  __shared__ unsigned short Ah[64][LDK];
  __shared__ unsigned short Bd[64][LDK];

  const int n0 = blockIdx.x * 64, mt = blockIdx.y, z = blockIdx.z;
  int cnt, hb; const void* W; size_t woff = 0;
  if (z == 0) { cnt = T_TOK; hb = 0; W = Wsh; }
  else {
    const int e = z - 1;
    cnt = counts[e];
    if (mt * 64 >= cnt) return;
    hb = T_TOK;
    for (int i = 0; i < e; ++i) hb += counts[i];
    W = Wex; woff = (size_t)e * (DM * DFF);
  }

  const int tid = threadIdx.x;
  const int sr = tid >> 2;
  const int sc = (tid & 3) * 16;
  const int entry = mt * 64 + sr;
  const bool avalid = entry < cnt;
  const unsigned short* arow = Hall;
  if (avalid) arow = Hall + (size_t)(hb + entry) * DFF;
  const size_t doff = woff + (size_t)(n0 + sr) * DFF;

  const int lane = tid & 63;
  const int wm = ((tid >> 6) & 1) * 32;
  const int wn = ((tid >> 7) & 1) * 32;
  const int lr = lane & 15;
  const int qd = lane >> 4;

  const f32x4 z4 = {0.f, 0.f, 0.f, 0.f};
  f32x4 acc[2][2];
  #pragma unroll
  for (int i = 0; i < 2; ++i)
    #pragma unroll
    for (int j = 0; j < 2; ++j) acc[i][j] = z4;

  for (int k0 = 0; k0 < DFF; k0 += 64) {
    us8 av0 = {0,0,0,0,0,0,0,0}, av1 = {0,0,0,0,0,0,0,0};
    if (avalid) {
      av0 = *(const us8*)(arow + k0 + sc);
      av1 = *(const us8*)(arow + k0 + sc + 8);
    }
    us8 dv[2];
    stage16<PRE>(W, doff + k0 + sc, dv);
    __syncthreads();
    *(us8*)&Ah[sr][sc] = av0;   *(us8*)&Ah[sr][sc+8] = av1;
    *(us8*)&Bd[sr][sc] = dv[0]; *(us8*)&Bd[sr][sc+8] = dv[1];
    __syncthreads();
    #pragma unroll
    for (int ks = 0; ks < 2; ++ks) {
      const int kk = ks * 32 + qd * 8;
      bf16x8 a0 = *(const bf16x8*)&Ah[wm      + lr][kk];
      bf16x8 a1 = *(const bf16x8*)&Ah[wm + 16 + lr][kk];
      bf16x8 b0 = *(const bf16x8*)&Bd[wn      + lr][kk];
      bf16x8 b1 = *(const bf16x8*)&Bd[wn + 16 + lr][kk];
      acc[0][0] = MFMA(a0, b0, acc[0][0]);
      acc[0][1] = MFMA(a0, b1, acc[0][1]);
      acc[1][0] = MFMA(a1, b0, acc[1][0]);
      acc[1][1] = MFMA(a1, b1, acc[1][1]);
    }
  }

  #pragma unroll
  for (int sm = 0; sm < 2; ++sm)
    #pragma unroll
    for (int sn = 0; sn < 2; ++sn) {
      const int col = n0 + wn + sn * 16 + lr;
      #pragma unroll
      for (int r = 0; r < 4; ++r) {
        const int ent = mt * 64 + wm + sm * 16 + qd * 4 + r;
        if (ent < cnt) {
          float v = acc[sm][sn][r];
          if (z == 0) {
            atomicAdd(out + (size_t)ent * DM + col, v);
          } else {
            int   tok = list[(z - 1) * T_TOK + ent];
            float g   = wgt [(z - 1) * T_TOK + ent];
            atomicAdd(out + (size_t)tok * DM + col, g * v);
          }
        }
      }
    }
}

// ---------------------------------------------------------------------------
extern "C" void kernel_launch(void* const* d_in, const int* in_sizes, int n_in,
                              void* d_out, int out_size, void* d_ws, size_t ws_size,
                              hipStream_t stream) {
  const float* x    = (const float*)d_in[0];
  const float* gw   = (const float*)d_in[1];
  const float* bias = (const float*)d_in[2];
  const float* sgu  = (const float*)d_in[3];
  const float* sdn  = (const float*)d_in[4];
  const float* egu  = (const float*)d_in[5];
  const float* edn  = (const float*)d_in[6];
  float* out = (float*)d_out;

  // workspace layout (bytes)
  char* ws = (char*)d_ws;
  int*            counts = (int*)(ws + 0);        // 16 ints
  int*            list   = (int*)(ws + 64);       // 16*2048 ints
  float*          wgt    = (float*)(ws + 131136); // 16*2048 floats
  unsigned short* Hall   = (unsigned short*)(ws + 262208); // 8192*512 bf16 (shared rows 0..2047, routed after)
  // preconverted bf16 copies (PRE path only)
  unsigned short* xb   = (unsigned short*)(ws + 8650816);
  unsigned short* sgub = (unsigned short*)(ws + 10747968);
  unsigned short* sdnb = (unsigned short*)(ws + 11796544);
  unsigned short* egub = (unsigned short*)(ws + 12320832);
  unsigned short* ednb = (unsigned short*)(ws + 29098048);
  const size_t need_base = 8650816, need_pre = 37486656;
  if (ws_size < need_base) return;
  const bool pre = ws_size >= need_pre;

  hipMemsetAsync(counts, 0, 64, stream);
  hipMemsetAsync(out, 0, (size_t)out_size * sizeof(float), stream);
  router_kernel<<<512, 256, 0, stream>>>(x, gw, bias, counts, list, wgt);

  if (pre) {
    conv_kernel<<<7040, 256, 0, stream>>>(x, sgu, sdn, egu, edn,
                                          xb, sgub, sdnb, egub, ednb);
    gemm1_fused<true ><<<dim3(8, 32, NE + 1), 256, 0, stream>>>(xb, sgub, egub, Hall, counts, list);
    gemm2_fused<true ><<<dim3(8, 32, NE + 1), 256, 0, stream>>>(Hall, sdnb, ednb, out, counts, list, wgt);
  } else {
    gemm1_fused<false><<<dim3(8, 32, NE + 1), 256, 0, stream>>>(x, sgu, egu, Hall, counts, list);
    gemm2_fused<false><<<dim3(8, 32, NE + 1), 256, 0, stream>>>(Hall, sdn, edn, out, counts, list, wgt);
  }
}